// Round 12
// baseline (430.542 us; speedup 1.0000x reference)
//
#include <hip/hip_runtime.h>

#define NN 30000
#define NE 480000
#define CH 64
#define NH 4
#define BN_EPS 1e-5f
#define NBLK 7500   // NN/4 aggregate blocks (256 thr = 4 waves = 4 nodes)
#define SCB 118     // ceil(NN/256) scan blocks

// ---------------------------------------------------------------------------
// bf16 helpers (RNE pack, cheap unpack)
// ---------------------------------------------------------------------------
__device__ __forceinline__ unsigned short f2bf(float x) {
    unsigned int u = __float_as_uint(x);
    return (unsigned short)((u + 0x7fffu + ((u >> 16) & 1u)) >> 16);
}
__device__ __forceinline__ float bf2f(unsigned short h) {
    return __uint_as_float(((unsigned int)h) << 16);
}

// ---------------------------------------------------------------------------
// Inline int64-vs-int32 detect: for int64 data the odd 32-bit words are the
// high halves of values < 2^31 -> all zero. 8 consecutive zero odd words from
// random int32 node indices has probability ~(1/30000)^8 ~ 0.
// ---------------------------------------------------------------------------
__device__ __forceinline__ int detect64(const unsigned int* __restrict__ ei) {
    unsigned int v = ei[1] | ei[3] | ei[5] | ei[7] |
                     ei[9] | ei[11] | ei[13] | ei[15];
    return v == 0u;
}

__device__ __forceinline__ int load_idx(const void* ei, int is64, int pos) {
    if (is64) return (int)((const long long*)ei)[pos];
    return ((const int*)ei)[pos];
}

// ---------------------------------------------------------------------------
// Histogram of dst degrees (real edges only).
// ---------------------------------------------------------------------------
__global__ __launch_bounds__(256) void hist_kernel(const void* __restrict__ ei,
                                                   int* __restrict__ degi) {
    int e = blockIdx.x * 256 + threadIdx.x;
    if (e >= NE) return;
    int is64 = detect64((const unsigned int*)ei);
    int d = load_idx(ei, is64, NE + e);
    atomicAdd(&degi[d], 1);
}

// ---------------------------------------------------------------------------
// Scan phase A: per-block sums of degi -> bsum[SCB].
// ---------------------------------------------------------------------------
__global__ __launch_bounds__(256) void scanA_kernel(const int* __restrict__ degi,
                                                    int* __restrict__ bsum) {
    int t = blockIdx.x * 256 + threadIdx.x;
    int v = (t < NN) ? degi[t] : 0;
    __shared__ int sm[256];
    sm[threadIdx.x] = v;
    __syncthreads();
    for (int off = 128; off > 0; off >>= 1) {
        if (threadIdx.x < off) sm[threadIdx.x] += sm[threadIdx.x + off];
        __syncthreads();
    }
    if (threadIdx.x == 0) bsum[blockIdx.x] = sm[0];
}

// ---------------------------------------------------------------------------
// Scan phase B: one 128-thread block, exclusive scan of bsum -> boff.
// ---------------------------------------------------------------------------
__global__ __launch_bounds__(128) void scanB_kernel(const int* __restrict__ bsum,
                                                    int* __restrict__ boff) {
    __shared__ int sm[128];
    int t = threadIdx.x;
    int v = (t < SCB) ? bsum[t] : 0;
    sm[t] = v;
    __syncthreads();
    for (int off = 1; off < 128; off <<= 1) {
        int add = (t >= off) ? sm[t - off] : 0;
        __syncthreads();
        sm[t] += add;
        __syncthreads();
    }
    if (t < SCB) boff[t] = sm[t] - v;  // exclusive
}

// ---------------------------------------------------------------------------
// Scan phase C: rowptr[t] = boff[block] + exclusive-in-block scan of degi.
// ---------------------------------------------------------------------------
__global__ __launch_bounds__(256) void scanC_kernel(const int* __restrict__ degi,
                                                    const int* __restrict__ boff,
                                                    int* __restrict__ rowptr) {
    __shared__ int sm[256];
    int b = blockIdx.x;
    int t = b * 256 + threadIdx.x;
    int d = (t < NN) ? degi[t] : 0;
    sm[threadIdx.x] = d;
    __syncthreads();
    for (int off = 1; off < 256; off <<= 1) {
        int add = (threadIdx.x >= off) ? sm[threadIdx.x - off] : 0;
        __syncthreads();
        sm[threadIdx.x] += add;
        __syncthreads();
    }
    if (t < NN) rowptr[t] = boff[b] + sm[threadIdx.x] - d;  // exclusive
    if (b == 0 && threadIdx.x == 0) rowptr[NN] = NE;
}

// ---------------------------------------------------------------------------
// Scatter src indices into CSR slots. Rows fill in REVERSE via atomicSub on
// degi (degi is dead after scanC; within-row order is irrelevant).
// ---------------------------------------------------------------------------
__global__ __launch_bounds__(256) void scatter_kernel(const void* __restrict__ ei,
                                                      const int* __restrict__ rowptr,
                                                      int* __restrict__ degi,
                                                      int* __restrict__ csr) {
    int e = blockIdx.x * 256 + threadIdx.x;
    if (e >= NE) return;
    int is64 = detect64((const unsigned int*)ei);
    int s = load_idx(ei, is64, e);
    int d = load_idx(ei, is64, NE + e);
    int pos = rowptr[d] + atomicSub(&degi[d], 1) - 1;
    csr[pos] = s;
}

// ---------------------------------------------------------------------------
// One-shot prep: transpose W matrices into wt layout
//   wt[layer][(k*64 + l)*4 + m] = W_layer[(m*64 + l)*64 + k]
// plus pack U0 into u0pack[k*4+m] = U0[m*64+k], zero cst0[256], zero degi[NN].
// ---------------------------------------------------------------------------
__global__ __launch_bounds__(256) void transpose_kernel(const float* __restrict__ W0,
                                                        const float* __restrict__ W1,
                                                        const float* __restrict__ W2,
                                                        const float* __restrict__ U0,
                                                        float* __restrict__ wt,
                                                        float* __restrict__ u0pack,
                                                        float* __restrict__ cst0,
                                                        int* __restrict__ degi) {
    int t = blockIdx.x * 256 + threadIdx.x;
    if (t < 3 * 16384) {
        int layer = t / 16384;
        int r = t & 16383;
        int m = r & 3;
        int l = (r >> 2) & 63;
        int k = r >> 8;
        const float* W = (layer == 0) ? W0 : (layer == 1) ? W1 : W2;
        wt[t] = W[(m * 64 + l) * 64 + k];
    } else if (t < 3 * 16384 + 256) {
        int i = t - 3 * 16384;
        int k = i >> 2;
        int m = i & 3;
        u0pack[i] = U0[m * 64 + k];
    } else if (t < 3 * 16384 + 512) {
        cst0[t - 3 * 16384 - 256] = 0.0f;
    } else if (t < 3 * 16384 + 512 + NN) {
        degi[t - 3 * 16384 - 512] = 0;
    }
}

__device__ __forceinline__ float fold_sc_f(const float* stats, const float* g, int k) {
    const float invN = 1.0f / (float)NN;
    float mu = stats[k] * invN;
    float var = stats[64 + k] * invN - mu * mu;
    return rsqrtf(var + BN_EPS) * g[k];
}

// ---------------------------------------------------------------------------
// Node transform, optionally with BN-fold computed IN-KERNEL (per block, LDS):
//   sc[k] = g[k]*rsqrt(var+eps); sh[k] = bt[k]-mu[k]*sc[k]
//   y2[n][o] = bf16x4 of (h*sc)@wtT + cst,  cst[o2] = sum_k sh[k]*Wnext[o2,k]
//   p-tail uses usc[k*4+m] = Unext[m*64+k]*sc[k]
// DO_FOLD=0: raw weights (layer 0) with precomputed cst/usc arrays.
// Wave per 4 nodes; lane = channel. p tail: threads 0..63, one (node,head)
// each for the block's 16 nodes (R7 lesson: never compute p wave-uniformly).
// ---------------------------------------------------------------------------
template <int DO_FOLD>
__global__ __launch_bounds__(256) void transform_kernel(const float* __restrict__ h,
                                                        const float4* __restrict__ wt4,
                                                        const float* __restrict__ cst_g,
                                                        const float* __restrict__ usc_g,
                                                        const float* __restrict__ stats,
                                                        const float* __restrict__ g,
                                                        const float* __restrict__ bt,
                                                        const float* __restrict__ Wnext,
                                                        const float* __restrict__ Unext,
                                                        ushort4* __restrict__ y2,
                                                        float* __restrict__ pout) {
    __shared__ float sc_s[64];
    __shared__ float sh_s[64];
    __shared__ float cst_s[256];
    __shared__ float usc_s[256];

    if (DO_FOLD) {
        const float invN = 1.0f / (float)NN;
        if (threadIdx.x < 64) {
            int k = threadIdx.x;
            float sc = fold_sc_f(stats, g, k);
            sc_s[k] = sc;
            sh_s[k] = bt[k] - (stats[k] * invN) * sc;
        }
        __syncthreads();
        {   // cst: one output channel per thread (Wnext 64 KB, L2-hot)
            int o2 = threadIdx.x;
            float s = 0.0f;
            const float4* w4 = reinterpret_cast<const float4*>(Wnext + o2 * 64);
            const float4* sh4 = reinterpret_cast<const float4*>(sh_s);
#pragma unroll
            for (int k4 = 0; k4 < 16; ++k4) {
                float4 wv = w4[k4];
                float4 sv = sh4[k4];
                s += sv.x * wv.x + sv.y * wv.y + sv.z * wv.z + sv.w * wv.w;
            }
            cst_s[o2] = s;
            int k = o2 >> 2;
            int m = o2 & 3;
            usc_s[o2] = Unext[m * 64 + k] * sc_s[k];
        }
        __syncthreads();
    }

    int wave = (blockIdx.x * 256 + threadIdx.x) >> 6;  // 0..7499 (exact)
    int lane = threadIdx.x & 63;
    int n0 = wave * 4;
    const float4* h4 = reinterpret_cast<const float4*>(h);

    float acc[4][4];
#pragma unroll
    for (int j = 0; j < 4; ++j)
#pragma unroll
        for (int m = 0; m < 4; ++m) acc[j][m] = 0.0f;

#pragma unroll 4
    for (int kb = 0; kb < 16; ++kb) {
        float s0 = 1.0f, s1 = 1.0f, s2 = 1.0f, s3 = 1.0f;
        if (DO_FOLD) {
            s0 = sc_s[kb * 4 + 0];
            s1 = sc_s[kb * 4 + 1];
            s2 = sc_s[kb * 4 + 2];
            s3 = sc_s[kb * 4 + 3];
        }
        float hb[4][4];
#pragma unroll
        for (int j = 0; j < 4; ++j) {
            float4 v = h4[(size_t)(n0 + j) * 16 + kb];
            hb[j][0] = v.x * s0; hb[j][1] = v.y * s1;
            hb[j][2] = v.z * s2; hb[j][3] = v.w * s3;
        }
#pragma unroll
        for (int kk = 0; kk < 4; ++kk) {
            float4 wv = wt4[(size_t)(kb * 4 + kk) * 64 + lane];
#pragma unroll
            for (int j = 0; j < 4; ++j) {
                acc[j][0] += hb[j][kk] * wv.x;
                acc[j][1] += hb[j][kk] * wv.y;
                acc[j][2] += hb[j][kk] * wv.z;
                acc[j][3] += hb[j][kk] * wv.w;
            }
        }
    }
    float c0 = DO_FOLD ? cst_s[lane] : cst_g[lane];
    float c1 = DO_FOLD ? cst_s[64 + lane] : cst_g[64 + lane];
    float c2 = DO_FOLD ? cst_s[128 + lane] : cst_g[128 + lane];
    float c3 = DO_FOLD ? cst_s[192 + lane] : cst_g[192 + lane];
#pragma unroll
    for (int j = 0; j < 4; ++j) {
        ushort4 o;
        o.x = f2bf(acc[j][0] + c0);
        o.y = f2bf(acc[j][1] + c1);
        o.z = f2bf(acc[j][2] + c2);
        o.w = f2bf(acc[j][3] + c3);
        y2[(size_t)(n0 + j) * 64 + lane] = o;
    }

    // p tail: block covers 16 nodes exactly (1875 * 16 = 30000)
    if (threadIdx.x < 64) {
        int n = blockIdx.x * 16 + (threadIdx.x >> 2);
        int m = threadIdx.x & 3;
        const float4* hn = h4 + (size_t)n * 16;
        const float* uu = DO_FOLD ? usc_s : usc_g;
        float a = 0.0f;
#pragma unroll
        for (int j = 0; j < 16; ++j) {
            float4 hv = hn[j];
            a += hv.x * uu[(4 * j + 0) * 4 + m] + hv.y * uu[(4 * j + 1) * 4 + m] +
                 hv.z * uu[(4 * j + 2) * 4 + m] + hv.w * uu[(4 * j + 3) * 4 + m];
        }
        pout[n * 4 + m] = a;
    }
}

// ---------------------------------------------------------------------------
// Fused aggregate (R10 4-wide version — 8-wide regressed via VGPR/occupancy).
// One wave per dst node, lane = output channel.
// Phase 1: each lane computes ONE edge's normalized attention (softmax w/
// max-sub — REQUIRED, see R5 NaN) into LDS. Phase 2: 4-wide gather+FMA.
// ---------------------------------------------------------------------------
template <int DO_RELU_STATS>
__global__ __launch_bounds__(256) void aggregate_kernel(const int* __restrict__ rowptr,
                                                        const int* __restrict__ csr,
                                                        const float* __restrict__ p,
                                                        const ushort4* __restrict__ y2,
                                                        const float* __restrict__ cvec,
                                                        const float* __restrict__ bvec,
                                                        float* __restrict__ hout,
                                                        float* __restrict__ partial) {
    __shared__ float4 attn_s[4][64];
    __shared__ int src_s[4][64];
    int wid = threadIdx.x >> 6;
    int lane = threadIdx.x & 63;
    int n = blockIdx.x * 4 + wid;
    const float4* p4 = reinterpret_cast<const float4*>(p);

    float4 cv = make_float4(cvec[0], cvec[1], cvec[2], cvec[3]);
    float4 pd = p4[n];
    float4 pdc = make_float4(pd.x + cv.x, pd.y + cv.y, pd.z + cv.z, pd.w + cv.w);

    // self-loop attention = softmax(c), node-independent
    float smx = fmaxf(fmaxf(cv.x, cv.y), fmaxf(cv.z, cv.w));
    float se0 = __expf(cv.x - smx), se1 = __expf(cv.y - smx);
    float se2 = __expf(cv.z - smx), se3 = __expf(cv.w - smx);
    float sinv = 1.0f / (se0 + se1 + se2 + se3);
    ushort4 ws = y2[(unsigned)(n * 64 + lane)];
    float acc0 = (se0 * bf2f(ws.x) + se1 * bf2f(ws.y) +
                  se2 * bf2f(ws.z) + se3 * bf2f(ws.w)) * sinv;
    float acc1 = 0.0f, acc2 = 0.0f, acc3 = 0.0f;

    int start = rowptr[n];
    int end = rowptr[n + 1];
    for (int j = start; j < end; j += 64) {
        int chunk = end - j;
        if (chunk > 64) chunk = 64;
        if (lane < chunk) {
            int s = csr[j + lane];
            float4 q = p4[(unsigned)s];
            float l0 = pdc.x - q.x;
            float l1 = pdc.y - q.y;
            float l2 = pdc.z - q.z;
            float l3 = pdc.w - q.w;
            float mx = fmaxf(fmaxf(l0, l1), fmaxf(l2, l3));
            float e0 = __expf(l0 - mx);
            float e1 = __expf(l1 - mx);
            float e2 = __expf(l2 - mx);
            float e3 = __expf(l3 - mx);
            float inv = 1.0f / (e0 + e1 + e2 + e3);
            attn_s[wid][lane] = make_float4(e0 * inv, e1 * inv, e2 * inv, e3 * inv);
            src_s[wid][lane] = s;
        }
        int k = 0;
        for (; k + 4 <= chunk; k += 4) {
            float4 a0 = attn_s[wid][k];
            int s0 = src_s[wid][k];
            float4 a1 = attn_s[wid][k + 1];
            int s1 = src_s[wid][k + 1];
            float4 a2 = attn_s[wid][k + 2];
            int s2 = src_s[wid][k + 2];
            float4 a3 = attn_s[wid][k + 3];
            int s3 = src_s[wid][k + 3];
            ushort4 w0 = y2[(unsigned)(s0 * 64 + lane)];
            ushort4 w1 = y2[(unsigned)(s1 * 64 + lane)];
            ushort4 w2 = y2[(unsigned)(s2 * 64 + lane)];
            ushort4 w3 = y2[(unsigned)(s3 * 64 + lane)];
            acc0 += a0.x * bf2f(w0.x) + a0.y * bf2f(w0.y) +
                    a0.z * bf2f(w0.z) + a0.w * bf2f(w0.w);
            acc1 += a1.x * bf2f(w1.x) + a1.y * bf2f(w1.y) +
                    a1.z * bf2f(w1.z) + a1.w * bf2f(w1.w);
            acc2 += a2.x * bf2f(w2.x) + a2.y * bf2f(w2.y) +
                    a2.z * bf2f(w2.z) + a2.w * bf2f(w2.w);
            acc3 += a3.x * bf2f(w3.x) + a3.y * bf2f(w3.y) +
                    a3.z * bf2f(w3.z) + a3.w * bf2f(w3.w);
        }
        for (; k < chunk; ++k) {
            float4 a0 = attn_s[wid][k];
            int s0 = src_s[wid][k];
            ushort4 w0 = y2[(unsigned)(s0 * 64 + lane)];
            acc0 += a0.x * bf2f(w0.x) + a0.y * bf2f(w0.y) +
                    a0.z * bf2f(w0.z) + a0.w * bf2f(w0.w);
        }
    }

    float val = ((acc0 + acc1) + (acc2 + acc3)) / (float)(end - start + 1) + bvec[lane];

    if (DO_RELU_STATS) {
        val = fmaxf(val, 0.0f);
        hout[(size_t)n * 64 + lane] = val;
        __shared__ float s1m[256];
        __shared__ float s2m[256];
        s1m[threadIdx.x] = val;
        s2m[threadIdx.x] = val * val;
        __syncthreads();
        if (threadIdx.x < 64) {
            float s = s1m[threadIdx.x] + s1m[threadIdx.x + 64] +
                      s1m[threadIdx.x + 128] + s1m[threadIdx.x + 192];
            float q = s2m[threadIdx.x] + s2m[threadIdx.x + 64] +
                      s2m[threadIdx.x + 128] + s2m[threadIdx.x + 192];
            partial[blockIdx.x * 128 + threadIdx.x] = s;
            partial[blockIdx.x * 128 + 64 + threadIdx.x] = q;
        }
    } else {
        hout[(size_t)n * 64 + lane] = val;
    }
}

// ---------------------------------------------------------------------------
// Reduce per-block partials -> stats[128]. One block per slot.
// ---------------------------------------------------------------------------
__global__ __launch_bounds__(256) void reduce_kernel(const float* __restrict__ partial,
                                                     float* __restrict__ stats) {
    int slot = blockIdx.x;           // 0..127
    float acc = 0.0f;
    for (int j = threadIdx.x; j < NBLK; j += 256)
        acc += partial[(size_t)j * 128 + slot];
    __shared__ float sm[256];
    sm[threadIdx.x] = acc;
    __syncthreads();
    for (int off = 128; off > 0; off >>= 1) {
        if (threadIdx.x < off) sm[threadIdx.x] += sm[threadIdx.x + off];
        __syncthreads();
    }
    if (threadIdx.x == 0) stats[slot] = sm[0];
}

extern "C" void kernel_launch(void* const* d_in, const int* in_sizes, int n_in,
                              void* d_out, int out_size, void* d_ws, size_t ws_size,
                              hipStream_t stream) {
    const float* x = (const float*)d_in[0];
    const void* ei = d_in[1];
    const float* W0 = (const float*)d_in[2];
    const float* U0 = (const float*)d_in[3];
    const float* c0 = (const float*)d_in[4];
    const float* b0 = (const float*)d_in[5];
    const float* g0 = (const float*)d_in[6];
    const float* bt0 = (const float*)d_in[7];
    const float* W1 = (const float*)d_in[8];
    const float* U1 = (const float*)d_in[9];
    const float* c1 = (const float*)d_in[10];
    const float* b1 = (const float*)d_in[11];
    const float* g1 = (const float*)d_in[12];
    const float* bt1 = (const float*)d_in[13];
    const float* W2 = (const float*)d_in[14];
    const float* U2 = (const float*)d_in[15];
    const float* c2 = (const float*)d_in[16];
    const float* b2 = (const float*)d_in[17];

    float* ws = (float*)d_ws;
    float* wt = ws;                          // 3*16384
    float* u0pack = wt + 3 * 16384;          // 256
    float* cst0 = u0pack + 256;              // 256
    ushort4* y2 = (ushort4*)(cst0 + 256);    // NN*64 ushort4 (15.36 MB)
    float* p = (float*)((unsigned short*)y2 + (size_t)NN * 256);  // NN*4
    float* h1 = p + (size_t)NN * 4;          // NN*64
    float* h2 = h1 + (size_t)NN * 64;        // NN*64
    float* stats = h2 + (size_t)NN * 64;     // 128
    float* partial = stats + 128;            // NBLK*128
    int* degi = (int*)(partial + (size_t)NBLK * 128);  // NN
    int* rowptr = degi + NN;                 // NN+1
    int* csr = rowptr + NN + 1;              // NE
    int* bsum = csr + NE;                    // SCB
    int* boff = bsum + SCB;                  // SCB

    const int TB = 256;
    const int tfBlocks = (NN / 4) * 64 / TB;         // 1875 exact
    const int aggBlocks = NBLK;                      // 7500 (wave per node)
    const int eBlocks = NE / TB;                     // 1875 exact
    const int trBlocks = (3 * 16384 + 512 + NN + TB - 1) / TB;  // 312

    // ---- one-shot prep: weight repack + degi zero, CSR by dst ----
    transpose_kernel<<<trBlocks, TB, 0, stream>>>(W0, W1, W2, U0, wt, u0pack, cst0, degi);
    hist_kernel<<<eBlocks, TB, 0, stream>>>(ei, degi);
    scanA_kernel<<<SCB, TB, 0, stream>>>(degi, bsum);
    scanB_kernel<<<1, 128, 0, stream>>>(bsum, boff);
    scanC_kernel<<<SCB, TB, 0, stream>>>(degi, boff, rowptr);
    scatter_kernel<<<eBlocks, TB, 0, stream>>>(ei, rowptr, degi, csr);

    const float4* wt4_0 = reinterpret_cast<const float4*>(wt);
    const float4* wt4_1 = wt4_0 + 4096;
    const float4* wt4_2 = wt4_1 + 4096;

    // ---- layer 0 (raw W0/U0, zero cst) ----
    transform_kernel<0><<<tfBlocks, TB, 0, stream>>>(x, wt4_0, cst0, u0pack,
                                                     nullptr, nullptr, nullptr,
                                                     nullptr, nullptr, y2, p);
    aggregate_kernel<1><<<aggBlocks, TB, 0, stream>>>(rowptr, csr, p, y2, c0, b0, h1, partial);
    reduce_kernel<<<128, TB, 0, stream>>>(partial, stats);

    // ---- layer 1 (BN0 folded in-kernel into W1/U1) ----
    transform_kernel<1><<<tfBlocks, TB, 0, stream>>>(h1, wt4_1, nullptr, nullptr,
                                                     stats, g0, bt0, W1, U1, y2, p);
    aggregate_kernel<1><<<aggBlocks, TB, 0, stream>>>(rowptr, csr, p, y2, c1, b1, h2, partial);
    reduce_kernel<<<128, TB, 0, stream>>>(partial, stats);

    // ---- layer 2 (BN1 folded in-kernel into W2/U2) ----
    transform_kernel<1><<<tfBlocks, TB, 0, stream>>>(h2, wt4_2, nullptr, nullptr,
                                                     stats, g1, bt1, W2, U2, y2, p);
    aggregate_kernel<0><<<aggBlocks, TB, 0, stream>>>(rowptr, csr, p, y2, c2, b2, (float*)d_out, nullptr);
}

// Round 13
// 396.382 us; speedup vs baseline: 1.0862x; 1.0862x over previous
//
#include <hip/hip_runtime.h>

#define NN 30000
#define NE 480000
#define CH 64
#define NH 4
#define BN_EPS 1e-5f
#define NBLK 7500   // NN/4 aggregate blocks (256 thr = 4 waves = 4 nodes)
#define SCB 118     // ceil(NN/256) scan blocks

// ---------------------------------------------------------------------------
// bf16 helpers (RNE pack, cheap unpack)
// ---------------------------------------------------------------------------
__device__ __forceinline__ unsigned short f2bf(float x) {
    unsigned int u = __float_as_uint(x);
    return (unsigned short)((u + 0x7fffu + ((u >> 16) & 1u)) >> 16);
}
__device__ __forceinline__ float bf2f(unsigned short h) {
    return __uint_as_float(((unsigned int)h) << 16);
}

// ---------------------------------------------------------------------------
// Inline int64-vs-int32 detect: for int64 data the odd 32-bit words are the
// high halves of values < 2^31 -> all zero. 8 consecutive zero odd words from
// random int32 node indices has probability ~(1/30000)^8 ~ 0.
// ---------------------------------------------------------------------------
__device__ __forceinline__ int detect64(const unsigned int* __restrict__ ei) {
    unsigned int v = ei[1] | ei[3] | ei[5] | ei[7] |
                     ei[9] | ei[11] | ei[13] | ei[15];
    return v == 0u;
}

__device__ __forceinline__ int load_idx(const void* ei, int is64, int pos) {
    if (is64) return (int)((const long long*)ei)[pos];
    return ((const int*)ei)[pos];
}

// ---------------------------------------------------------------------------
// Histogram of dst degrees (real edges only).
// ---------------------------------------------------------------------------
__global__ __launch_bounds__(256) void hist_kernel(const void* __restrict__ ei,
                                                   int* __restrict__ degi) {
    int e = blockIdx.x * 256 + threadIdx.x;
    if (e >= NE) return;
    int is64 = detect64((const unsigned int*)ei);
    int d = load_idx(ei, is64, NE + e);
    atomicAdd(&degi[d], 1);
}

// ---------------------------------------------------------------------------
// Scan phase A: per-block sums of degi -> bsum[SCB].
// ---------------------------------------------------------------------------
__global__ __launch_bounds__(256) void scanA_kernel(const int* __restrict__ degi,
                                                    int* __restrict__ bsum) {
    int t = blockIdx.x * 256 + threadIdx.x;
    int v = (t < NN) ? degi[t] : 0;
    __shared__ int sm[256];
    sm[threadIdx.x] = v;
    __syncthreads();
    for (int off = 128; off > 0; off >>= 1) {
        if (threadIdx.x < off) sm[threadIdx.x] += sm[threadIdx.x + off];
        __syncthreads();
    }
    if (threadIdx.x == 0) bsum[blockIdx.x] = sm[0];
}

// ---------------------------------------------------------------------------
// Scan phase B: one 128-thread block, exclusive scan of bsum -> boff.
// ---------------------------------------------------------------------------
__global__ __launch_bounds__(128) void scanB_kernel(const int* __restrict__ bsum,
                                                    int* __restrict__ boff) {
    __shared__ int sm[128];
    int t = threadIdx.x;
    int v = (t < SCB) ? bsum[t] : 0;
    sm[t] = v;
    __syncthreads();
    for (int off = 1; off < 128; off <<= 1) {
        int add = (t >= off) ? sm[t - off] : 0;
        __syncthreads();
        sm[t] += add;
        __syncthreads();
    }
    if (t < SCB) boff[t] = sm[t] - v;  // exclusive
}

// ---------------------------------------------------------------------------
// Scan phase C: rowptr[t] = boff[block] + exclusive-in-block scan of degi.
// ---------------------------------------------------------------------------
__global__ __launch_bounds__(256) void scanC_kernel(const int* __restrict__ degi,
                                                    const int* __restrict__ boff,
                                                    int* __restrict__ rowptr) {
    __shared__ int sm[256];
    int b = blockIdx.x;
    int t = b * 256 + threadIdx.x;
    int d = (t < NN) ? degi[t] : 0;
    sm[threadIdx.x] = d;
    __syncthreads();
    for (int off = 1; off < 256; off <<= 1) {
        int add = (threadIdx.x >= off) ? sm[threadIdx.x - off] : 0;
        __syncthreads();
        sm[threadIdx.x] += add;
        __syncthreads();
    }
    if (t < NN) rowptr[t] = boff[b] + sm[threadIdx.x] - d;  // exclusive
    if (b == 0 && threadIdx.x == 0) rowptr[NN] = NE;
}

// ---------------------------------------------------------------------------
// Scatter src indices into CSR slots. Rows fill in REVERSE via atomicSub on
// degi (degi is dead after scanC; within-row order is irrelevant).
// ---------------------------------------------------------------------------
__global__ __launch_bounds__(256) void scatter_kernel(const void* __restrict__ ei,
                                                      const int* __restrict__ rowptr,
                                                      int* __restrict__ degi,
                                                      int* __restrict__ csr) {
    int e = blockIdx.x * 256 + threadIdx.x;
    if (e >= NE) return;
    int is64 = detect64((const unsigned int*)ei);
    int s = load_idx(ei, is64, e);
    int d = load_idx(ei, is64, NE + e);
    int pos = rowptr[d] + atomicSub(&degi[d], 1) - 1;
    csr[pos] = s;
}

// ---------------------------------------------------------------------------
// One-shot prep: transpose W matrices into wt layout
//   wt[layer][(k*64 + l)*4 + m] = W_layer[(m*64 + l)*64 + k]
// plus pack U0 into u0pack[k*4+m] = U0[m*64+k], zero cst0[256], zero degi[NN].
// ---------------------------------------------------------------------------
__global__ __launch_bounds__(256) void transpose_kernel(const float* __restrict__ W0,
                                                        const float* __restrict__ W1,
                                                        const float* __restrict__ W2,
                                                        const float* __restrict__ U0,
                                                        float* __restrict__ wt,
                                                        float* __restrict__ u0pack,
                                                        float* __restrict__ cst0,
                                                        int* __restrict__ degi) {
    int t = blockIdx.x * 256 + threadIdx.x;
    if (t < 3 * 16384) {
        int layer = t / 16384;
        int r = t & 16383;
        int m = r & 3;
        int l = (r >> 2) & 63;
        int k = r >> 8;
        const float* W = (layer == 0) ? W0 : (layer == 1) ? W1 : W2;
        wt[t] = W[(m * 64 + l) * 64 + k];
    } else if (t < 3 * 16384 + 256) {
        int i = t - 3 * 16384;
        int k = i >> 2;
        int m = i & 3;
        u0pack[i] = U0[m * 64 + k];
    } else if (t < 3 * 16384 + 512) {
        cst0[t - 3 * 16384 - 256] = 0.0f;
    } else if (t < 3 * 16384 + 512 + NN) {
        degi[t - 3 * 16384 - 512] = 0;
    }
}

// ---------------------------------------------------------------------------
// BN fold (separate kernel — R12's in-transform fold cost 45 µs/layer via
// VGPR/occupancy + in-loop LDS reads; keep it standalone):
//   sc[k] = g[k]*rsqrt(var+eps); sh[k] = bt[k]-mu[k]*sc[k]
//   wsc = wt_next*sc[k]; cst[o2] = sum_k sh[k]*Wnext[o2*64+k];
//   usc[k*4+m] = Unext[m*64+k]*sc[k]  (p shift cancels in logit differences)
// ---------------------------------------------------------------------------
__device__ __forceinline__ float fold_sc(const float* stats, const float* g, int k) {
    const float invN = 1.0f / (float)NN;
    float mu = stats[k] * invN;
    float var = stats[64 + k] * invN - mu * mu;
    return rsqrtf(var + BN_EPS) * g[k];
}

__global__ __launch_bounds__(256) void fold_kernel(const float* __restrict__ stats,
                                                   const float* __restrict__ g,
                                                   const float* __restrict__ bt,
                                                   const float* __restrict__ Wnext,
                                                   const float* __restrict__ Unext,
                                                   const float* __restrict__ wt_next,
                                                   float* __restrict__ wsc,
                                                   float* __restrict__ usc,
                                                   float* __restrict__ cst) {
    int t = blockIdx.x * 256 + threadIdx.x;
    const float invN = 1.0f / (float)NN;
    if (t < 16384) {
        int k = t >> 8;
        wsc[t] = wt_next[t] * fold_sc(stats, g, k);
    } else if (t < 16384 + 256) {
        int o2 = t - 16384;
        float s = 0.0f;
        for (int k = 0; k < 64; ++k) {
            float mu = stats[k] * invN;
            float sc = fold_sc(stats, g, k);
            float sh = bt[k] - mu * sc;
            s += sh * Wnext[o2 * 64 + k];
        }
        cst[o2] = s;
    } else if (t < 16384 + 512) {
        int i = t - 16384 - 256;
        int k = i >> 2;
        int m = i & 3;
        usc[i] = Unext[m * 64 + k] * fold_sc(stats, g, k);
    }
}

// ---------------------------------------------------------------------------
// Node transform (R10 tuned shape): y2[n][o] = bf16x4 of h@wtT (+cst).
// Wave per 4 nodes; lane = channel. p tail: threads 0..63, one (node,head)
// each for the block's 16 nodes (R7 lesson: never compute p wave-uniformly).
// ---------------------------------------------------------------------------
__global__ __launch_bounds__(256) void transform_kernel(const float* __restrict__ h,
                                                        const float4* __restrict__ wt4,
                                                        const float* __restrict__ cst,
                                                        const float* __restrict__ usc,
                                                        ushort4* __restrict__ y2,
                                                        float* __restrict__ pout) {
    int wave = (blockIdx.x * 256 + threadIdx.x) >> 6;  // 0..7499 (exact)
    int lane = threadIdx.x & 63;
    int n0 = wave * 4;
    const float4* h4 = reinterpret_cast<const float4*>(h);

    float acc[4][4];
#pragma unroll
    for (int j = 0; j < 4; ++j)
#pragma unroll
        for (int m = 0; m < 4; ++m) acc[j][m] = 0.0f;

#pragma unroll 4
    for (int kb = 0; kb < 16; ++kb) {
        float hb[4][4];
#pragma unroll
        for (int j = 0; j < 4; ++j) {
            float4 v = h4[(size_t)(n0 + j) * 16 + kb];
            hb[j][0] = v.x; hb[j][1] = v.y; hb[j][2] = v.z; hb[j][3] = v.w;
        }
#pragma unroll
        for (int kk = 0; kk < 4; ++kk) {
            float4 wv = wt4[(size_t)(kb * 4 + kk) * 64 + lane];
#pragma unroll
            for (int j = 0; j < 4; ++j) {
                acc[j][0] += hb[j][kk] * wv.x;
                acc[j][1] += hb[j][kk] * wv.y;
                acc[j][2] += hb[j][kk] * wv.z;
                acc[j][3] += hb[j][kk] * wv.w;
            }
        }
    }
    float c0 = cst[lane];
    float c1 = cst[64 + lane];
    float c2 = cst[128 + lane];
    float c3 = cst[192 + lane];
#pragma unroll
    for (int j = 0; j < 4; ++j) {
        ushort4 o;
        o.x = f2bf(acc[j][0] + c0);
        o.y = f2bf(acc[j][1] + c1);
        o.z = f2bf(acc[j][2] + c2);
        o.w = f2bf(acc[j][3] + c3);
        y2[(size_t)(n0 + j) * 64 + lane] = o;
    }

    // p tail: block covers 16 nodes exactly (1875 * 16 = 30000)
    if (threadIdx.x < 64) {
        int n = blockIdx.x * 16 + (threadIdx.x >> 2);
        int m = threadIdx.x & 3;
        const float4* hn = h4 + (size_t)n * 16;
        float a = 0.0f;
#pragma unroll
        for (int j = 0; j < 16; ++j) {
            float4 hv = hn[j];
            a += hv.x * usc[(4 * j + 0) * 4 + m] + hv.y * usc[(4 * j + 1) * 4 + m] +
                 hv.z * usc[(4 * j + 2) * 4 + m] + hv.w * usc[(4 * j + 3) * 4 + m];
        }
        pout[n * 4 + m] = a;
    }
}

// ---------------------------------------------------------------------------
// Fused aggregate (R10 4-wide — 8-wide regressed via VGPR/occupancy, R11).
// One wave per dst node, lane = output channel.
// Phase 1: each lane computes ONE edge's normalized attention (softmax w/
// max-sub — REQUIRED, see R5 NaN) into LDS. Phase 2: 4-wide gather+FMA.
// ---------------------------------------------------------------------------
template <int DO_RELU_STATS>
__global__ __launch_bounds__(256) void aggregate_kernel(const int* __restrict__ rowptr,
                                                        const int* __restrict__ csr,
                                                        const float* __restrict__ p,
                                                        const ushort4* __restrict__ y2,
                                                        const float* __restrict__ cvec,
                                                        const float* __restrict__ bvec,
                                                        float* __restrict__ hout,
                                                        float* __restrict__ partial) {
    __shared__ float4 attn_s[4][64];
    __shared__ int src_s[4][64];
    int wid = threadIdx.x >> 6;
    int lane = threadIdx.x & 63;
    int n = blockIdx.x * 4 + wid;
    const float4* p4 = reinterpret_cast<const float4*>(p);

    float4 cv = make_float4(cvec[0], cvec[1], cvec[2], cvec[3]);
    float4 pd = p4[n];
    float4 pdc = make_float4(pd.x + cv.x, pd.y + cv.y, pd.z + cv.z, pd.w + cv.w);

    // self-loop attention = softmax(c), node-independent
    float smx = fmaxf(fmaxf(cv.x, cv.y), fmaxf(cv.z, cv.w));
    float se0 = __expf(cv.x - smx), se1 = __expf(cv.y - smx);
    float se2 = __expf(cv.z - smx), se3 = __expf(cv.w - smx);
    float sinv = 1.0f / (se0 + se1 + se2 + se3);
    ushort4 ws = y2[(unsigned)(n * 64 + lane)];
    float acc0 = (se0 * bf2f(ws.x) + se1 * bf2f(ws.y) +
                  se2 * bf2f(ws.z) + se3 * bf2f(ws.w)) * sinv;
    float acc1 = 0.0f, acc2 = 0.0f, acc3 = 0.0f;

    int start = rowptr[n];
    int end = rowptr[n + 1];
    for (int j = start; j < end; j += 64) {
        int chunk = end - j;
        if (chunk > 64) chunk = 64;
        if (lane < chunk) {
            int s = csr[j + lane];
            float4 q = p4[(unsigned)s];
            float l0 = pdc.x - q.x;
            float l1 = pdc.y - q.y;
            float l2 = pdc.z - q.z;
            float l3 = pdc.w - q.w;
            float mx = fmaxf(fmaxf(l0, l1), fmaxf(l2, l3));
            float e0 = __expf(l0 - mx);
            float e1 = __expf(l1 - mx);
            float e2 = __expf(l2 - mx);
            float e3 = __expf(l3 - mx);
            float inv = 1.0f / (e0 + e1 + e2 + e3);
            attn_s[wid][lane] = make_float4(e0 * inv, e1 * inv, e2 * inv, e3 * inv);
            src_s[wid][lane] = s;
        }
        int k = 0;
        for (; k + 4 <= chunk; k += 4) {
            float4 a0 = attn_s[wid][k];
            int s0 = src_s[wid][k];
            float4 a1 = attn_s[wid][k + 1];
            int s1 = src_s[wid][k + 1];
            float4 a2 = attn_s[wid][k + 2];
            int s2 = src_s[wid][k + 2];
            float4 a3 = attn_s[wid][k + 3];
            int s3 = src_s[wid][k + 3];
            ushort4 w0 = y2[(unsigned)(s0 * 64 + lane)];
            ushort4 w1 = y2[(unsigned)(s1 * 64 + lane)];
            ushort4 w2 = y2[(unsigned)(s2 * 64 + lane)];
            ushort4 w3 = y2[(unsigned)(s3 * 64 + lane)];
            acc0 += a0.x * bf2f(w0.x) + a0.y * bf2f(w0.y) +
                    a0.z * bf2f(w0.z) + a0.w * bf2f(w0.w);
            acc1 += a1.x * bf2f(w1.x) + a1.y * bf2f(w1.y) +
                    a1.z * bf2f(w1.z) + a1.w * bf2f(w1.w);
            acc2 += a2.x * bf2f(w2.x) + a2.y * bf2f(w2.y) +
                    a2.z * bf2f(w2.z) + a2.w * bf2f(w2.w);
            acc3 += a3.x * bf2f(w3.x) + a3.y * bf2f(w3.y) +
                    a3.z * bf2f(w3.z) + a3.w * bf2f(w3.w);
        }
        for (; k < chunk; ++k) {
            float4 a0 = attn_s[wid][k];
            int s0 = src_s[wid][k];
            ushort4 w0 = y2[(unsigned)(s0 * 64 + lane)];
            acc0 += a0.x * bf2f(w0.x) + a0.y * bf2f(w0.y) +
                    a0.z * bf2f(w0.z) + a0.w * bf2f(w0.w);
        }
    }

    float val = ((acc0 + acc1) + (acc2 + acc3)) / (float)(end - start + 1) + bvec[lane];

    if (DO_RELU_STATS) {
        val = fmaxf(val, 0.0f);
        hout[(size_t)n * 64 + lane] = val;
        __shared__ float s1m[256];
        __shared__ float s2m[256];
        s1m[threadIdx.x] = val;
        s2m[threadIdx.x] = val * val;
        __syncthreads();
        if (threadIdx.x < 64) {
            float s = s1m[threadIdx.x] + s1m[threadIdx.x + 64] +
                      s1m[threadIdx.x + 128] + s1m[threadIdx.x + 192];
            float q = s2m[threadIdx.x] + s2m[threadIdx.x + 64] +
                      s2m[threadIdx.x + 128] + s2m[threadIdx.x + 192];
            partial[blockIdx.x * 128 + threadIdx.x] = s;
            partial[blockIdx.x * 128 + 64 + threadIdx.x] = q;
        }
    } else {
        hout[(size_t)n * 64 + lane] = val;
    }
}

// ---------------------------------------------------------------------------
// Reduce per-block partials -> stats[128]. One block per slot.
// ---------------------------------------------------------------------------
__global__ __launch_bounds__(256) void reduce_kernel(const float* __restrict__ partial,
                                                     float* __restrict__ stats) {
    int slot = blockIdx.x;           // 0..127
    float acc = 0.0f;
    for (int j = threadIdx.x; j < NBLK; j += 256)
        acc += partial[(size_t)j * 128 + slot];
    __shared__ float sm[256];
    sm[threadIdx.x] = acc;
    __syncthreads();
    for (int off = 128; off > 0; off >>= 1) {
        if (threadIdx.x < off) sm[threadIdx.x] += sm[threadIdx.x + off];
        __syncthreads();
    }
    if (threadIdx.x == 0) stats[slot] = sm[0];
}

extern "C" void kernel_launch(void* const* d_in, const int* in_sizes, int n_in,
                              void* d_out, int out_size, void* d_ws, size_t ws_size,
                              hipStream_t stream) {
    const float* x = (const float*)d_in[0];
    const void* ei = d_in[1];
    const float* W0 = (const float*)d_in[2];
    const float* U0 = (const float*)d_in[3];
    const float* c0 = (const float*)d_in[4];
    const float* b0 = (const float*)d_in[5];
    const float* g0 = (const float*)d_in[6];
    const float* bt0 = (const float*)d_in[7];
    const float* W1 = (const float*)d_in[8];
    const float* U1 = (const float*)d_in[9];
    const float* c1 = (const float*)d_in[10];
    const float* b1 = (const float*)d_in[11];
    const float* g1 = (const float*)d_in[12];
    const float* bt1 = (const float*)d_in[13];
    const float* W2 = (const float*)d_in[14];
    const float* U2 = (const float*)d_in[15];
    const float* c2 = (const float*)d_in[16];
    const float* b2 = (const float*)d_in[17];

    float* ws = (float*)d_ws;
    float* wt = ws;                          // 3*16384
    float* wsc = wt + 3 * 16384;             // 16384
    float* usc = wsc + 16384;                // 256
    float* cst = usc + 256;                  // 256
    float* u0pack = cst + 256;               // 256
    float* cst0 = u0pack + 256;              // 256
    ushort4* y2 = (ushort4*)(cst0 + 256);    // NN*64 ushort4 (15.36 MB)
    float* p = (float*)((unsigned short*)y2 + (size_t)NN * 256);  // NN*4
    float* h1 = p + (size_t)NN * 4;          // NN*64
    float* h2 = h1 + (size_t)NN * 64;        // NN*64
    float* stats = h2 + (size_t)NN * 64;     // 128
    float* partial = stats + 128;            // NBLK*128
    int* degi = (int*)(partial + (size_t)NBLK * 128);  // NN
    int* rowptr = degi + NN;                 // NN+1
    int* csr = rowptr + NN + 1;              // NE
    int* bsum = csr + NE;                    // SCB
    int* boff = bsum + SCB;                  // SCB

    const int TB = 256;
    const int tfBlocks = (NN / 4) * 64 / TB;         // 1875 exact
    const int aggBlocks = NBLK;                      // 7500 (wave per node)
    const int eBlocks = NE / TB;                     // 1875 exact
    const int trBlocks = (3 * 16384 + 512 + NN + TB - 1) / TB;  // 312
    const int foldBlocks = (16384 + 512 + TB - 1) / TB;         // 66

    // ---- one-shot prep: weight repack + degi zero, CSR by dst ----
    transpose_kernel<<<trBlocks, TB, 0, stream>>>(W0, W1, W2, U0, wt, u0pack, cst0, degi);
    hist_kernel<<<eBlocks, TB, 0, stream>>>(ei, degi);
    scanA_kernel<<<SCB, TB, 0, stream>>>(degi, bsum);
    scanB_kernel<<<1, 128, 0, stream>>>(bsum, boff);
    scanC_kernel<<<SCB, TB, 0, stream>>>(degi, boff, rowptr);
    scatter_kernel<<<eBlocks, TB, 0, stream>>>(ei, rowptr, degi, csr);

    const float4* wt4_0 = reinterpret_cast<const float4*>(wt);
    const float4* wsc4 = reinterpret_cast<const float4*>(wsc);

    // ---- layer 0 (no BN in front: raw W0/U0, zero cst) ----
    transform_kernel<<<tfBlocks, TB, 0, stream>>>(x, wt4_0, cst0, u0pack, y2, p);
    aggregate_kernel<1><<<aggBlocks, TB, 0, stream>>>(rowptr, csr, p, y2, c0, b0, h1, partial);
    reduce_kernel<<<128, TB, 0, stream>>>(partial, stats);
    fold_kernel<<<foldBlocks, TB, 0, stream>>>(stats, g0, bt0, W1, U1, wt + 16384, wsc, usc, cst);

    // ---- layer 1 (BN0 folded into W1/U1) ----
    transform_kernel<<<tfBlocks, TB, 0, stream>>>(h1, wsc4, cst, usc, y2, p);
    aggregate_kernel<1><<<aggBlocks, TB, 0, stream>>>(rowptr, csr, p, y2, c1, b1, h2, partial);
    reduce_kernel<<<128, TB, 0, stream>>>(partial, stats);
    fold_kernel<<<foldBlocks, TB, 0, stream>>>(stats, g1, bt1, W2, U2, wt + 2 * 16384, wsc, usc, cst);

    // ---- layer 2 (BN1 folded into W2/U2) ----
    transform_kernel<<<tfBlocks, TB, 0, stream>>>(h2, wsc4, cst, usc, y2, p);
    aggregate_kernel<0><<<aggBlocks, TB, 0, stream>>>(rowptr, csr, p, y2, c2, b2, (float*)d_out, nullptr);
}